// Round 1
// baseline (456.794 us; speedup 1.0000x reference)
//
#include <hip/hip_runtime.h>

// SoftClusterGaussianHead — one-pass moment formulation.
// B=8, N=4096, D=512, K=8.
// sigma = S2 + (S0-2)*S1^2 with S0=sum_n p, S1=sum_n p*x, S2=sum_n p*x^2.

typedef float v2f __attribute__((ext_vector_type(2)));

#define B_ 8
#define N_ 4096
#define D_ 512
#define K_ 8
#define EPS_ 1e-6f
#define NCOPY 8
#define CHUNKS 32          // blocks per b
#define WAVES 8            // per block
#define ROWS_PER_WAVE 16   // 128 rows/block / 8 waves

// ws layout (floats):
//  S  region: [copy][b][k][d][2]  (S1,S2 interleaved)
//  S0 region: [copy][b][k]
#define S_FLOATS (NCOPY * B_ * K_ * D_ * 2)
#define S0_OFF   S_FLOATS
#define WS_FLOATS (S_FLOATS + NCOPY * B_ * K_)

__global__ __launch_bounds__(512, 2)
void k1_accum(const float* __restrict__ x, const float* __restrict__ W,
              const float* __restrict__ bias, float* __restrict__ ws,
              int ncopy) {
  const int lane = threadIdx.x & 63;
  const int wave = threadIdx.x >> 6;
  const int b    = blockIdx.x >> 5;
  const int chunk= blockIdx.x & 31;
  const int m    = lane & 7;

  const int d0 = lane * 4;           // owned d: d0..d0+3 and 256+d0..256+d0+3

  // Preload W fragments: wk[dj][kp] = (W[d][2kp], W[d][2kp+1])
  v2f wk[8][4];
#pragma unroll
  for (int c = 0; c < 4; ++c) {
    const float4* wr0 = reinterpret_cast<const float4*>(&W[(d0 + c) * K_]);
    float4 wa = wr0[0], wb = wr0[1];
    wk[c][0] = (v2f){wa.x, wa.y}; wk[c][1] = (v2f){wa.z, wa.w};
    wk[c][2] = (v2f){wb.x, wb.y}; wk[c][3] = (v2f){wb.z, wb.w};
    const float4* wr1 = reinterpret_cast<const float4*>(&W[(256 + d0 + c) * K_]);
    float4 wc = wr1[0], wd = wr1[1];
    wk[4+c][0] = (v2f){wc.x, wc.y}; wk[4+c][1] = (v2f){wc.z, wc.w};
    wk[4+c][2] = (v2f){wd.x, wd.y}; wk[4+c][3] = (v2f){wd.z, wd.w};
  }
  const float biasv = bias[m];

  v2f acc[8][8];
#pragma unroll
  for (int dj = 0; dj < 8; ++dj)
#pragma unroll
    for (int k = 0; k < 8; ++k) acc[dj][k] = (v2f){0.f, 0.f};
  float s0acc = 0.f;

  const bool c0 = (lane & 1) != 0;
  const bool c1 = (lane & 2) != 0;
  const bool c2 = (lane & 4) != 0;

  const int row_base = chunk * (WAVES * ROWS_PER_WAVE) + wave * ROWS_PER_WAVE;
  const float* xb = x + (size_t)b * N_ * D_;

  // software-pipelined row loop
  const float4* xr = reinterpret_cast<const float4*>(&xb[(size_t)row_base * D_]);
  float4 xa = xr[lane];
  float4 xc = xr[64 + lane];

  for (int i = 0; i < ROWS_PER_WAVE; ++i) {
    // prefetch next row (clamped, no OOB)
    const int nrow = row_base + ((i + 1 < ROWS_PER_WAVE) ? i + 1 : i);
    const float4* xrn = reinterpret_cast<const float4*>(&xb[(size_t)nrow * D_]);
    float4 na = xrn[lane];
    float4 nc = xrn[64 + lane];

    float xv[8] = {xa.x, xa.y, xa.z, xa.w, xc.x, xc.y, xc.z, xc.w};

    // partial logits over owned d
    v2f qp[4] = {(v2f){0,0},(v2f){0,0},(v2f){0,0},(v2f){0,0}};
#pragma unroll
    for (int dj = 0; dj < 8; ++dj) {
      v2f xx = (v2f){xv[dj], xv[dj]};
#pragma unroll
      for (int kp = 0; kp < 4; ++kp) qp[kp] += wk[dj][kp] * xx;
    }
    float q0=qp[0].x,q1=qp[0].y,q2=qp[1].x,q3=qp[1].y;
    float q4=qp[2].x,q5=qp[2].y,q6=qp[3].x,q7=qp[3].y;

    // reduce-scatter butterfly: lane ends with full logit for k = lane&7
    float r0 = c0 ? q0 : q1, r1 = c0 ? q2 : q3, r2 = c0 ? q4 : q5, r3 = c0 ? q6 : q7;
    r0 = __shfl_xor(r0, 1, 64); r1 = __shfl_xor(r1, 1, 64);
    r2 = __shfl_xor(r2, 1, 64); r3 = __shfl_xor(r3, 1, 64);
    float a0 = (c0 ? q1 : q0) + r0, a1 = (c0 ? q3 : q2) + r1;
    float a2 = (c0 ? q5 : q4) + r2, a3 = (c0 ? q7 : q6) + r3;
    float s0g = c1 ? a0 : a1, s1g = c1 ? a2 : a3;
    s0g = __shfl_xor(s0g, 2, 64); s1g = __shfl_xor(s1g, 2, 64);
    float b0 = (c1 ? a1 : a0) + s0g, b1 = (c1 ? a3 : a2) + s1g;
    float g0 = c2 ? b0 : b1;
    g0 = __shfl_xor(g0, 4, 64);
    float t = (c2 ? b1 : b0) + g0;
    t += __shfl_xor(t, 8, 64);
    t += __shfl_xor(t, 16, 64);
    t += __shfl_xor(t, 32, 64);
    t += biasv;

    // softmax in transposed (one-k-per-lane) form
    float mx = fmaxf(t, __shfl_xor(t, 1, 64));
    mx = fmaxf(mx, __shfl_xor(mx, 2, 64));
    mx = fmaxf(mx, __shfl_xor(mx, 4, 64));
    float e = __expf(t - mx);
    float se = e + __shfl_xor(e, 1, 64);
    se += __shfl_xor(se, 2, 64);
    se += __shfl_xor(se, 4, 64);
    float pm = e * __builtin_amdgcn_rcpf(se);
    s0acc += pm;

    // gather p[0..7] to every lane: src = (lane & 0x18) | k within 32-half
    float p[8];
#define GATH(KK) p[KK] = __int_as_float(__builtin_amdgcn_ds_swizzle(__float_as_int(pm), ((KK) << 5) | 0x18))
    GATH(0); GATH(1); GATH(2); GATH(3); GATH(4); GATH(5); GATH(6); GATH(7);
#undef GATH

    // accumulate packed (S1,S2)
#pragma unroll
    for (int dj = 0; dj < 8; ++dj) {
      v2f m2 = (v2f){xv[dj], xv[dj] * xv[dj]};
#pragma unroll
      for (int k = 0; k < 8; ++k) {
        v2f pp = (v2f){p[k], p[k]};
        acc[dj][k] += m2 * pp;
      }
    }

    xa = na; xc = nc;
  }

  // flush to replicated global accumulators (copy = wave % ncopy)
  const int copy = wave % ncopy;
  float* Sb = ws + ((size_t)copy * B_ + b) * K_ * D_ * 2;
#pragma unroll
  for (int dj = 0; dj < 8; ++dj) {
    const int d = (dj < 4) ? (d0 + dj) : (256 + d0 + (dj - 4));
#pragma unroll
    for (int k = 0; k < 8; ++k) {
      float* dst = Sb + ((size_t)k * D_ + d) * 2;
      atomicAdd(dst,     acc[dj][k].x);
      atomicAdd(dst + 1, acc[dj][k].y);
    }
  }
  if (lane < 8) {
    atomicAdd(ws + S0_OFF + (copy * B_ + b) * K_ + lane, s0acc);
  }
}

__global__ __launch_bounds__(512)
void k2_final(const float* __restrict__ ws, const float* __restrict__ eps,
              float* __restrict__ out, int ncopy) {
  const int b = blockIdx.x;
  const int d = threadIdx.x;
  __shared__ float s0sh[K_];
  __shared__ float red[WAVES];

  if (threadIdx.x < K_) {
    float s = 0.f;
    for (int c = 0; c < ncopy; ++c) s += ws[S0_OFF + (c * B_ + b) * K_ + threadIdx.x];
    s0sh[threadIdx.x] = s;
  }
  __syncthreads();

  float pooled = 0.f, klp = 0.f;
#pragma unroll
  for (int k = 0; k < K_; ++k) {
    float S1 = 0.f, S2 = 0.f;
    for (int c = 0; c < ncopy; ++c) {
      const float* p = ws + ((((size_t)c * B_ + b) * K_ + k) * D_ + d) * 2;
      S1 += p[0]; S2 += p[1];
    }
    const float S0 = s0sh[k];
    float sigraw = S2 + (S0 - 2.f) * S1 * S1;
    float sig = fmaxf(sigraw, 0.f) + EPS_;
    float z = S1 + eps[((size_t)b * K_ + k) * D_ + d] * sqrtf(sig);
    pooled += z;
    klp += 1.f + logf(sig) - S1 * S1 - sigraw;
  }
  out[b * D_ + d] = pooled * (1.f / K_);

  // block-reduce klp and accumulate the KL scalar
  klp += __shfl_xor(klp, 1, 64);
  klp += __shfl_xor(klp, 2, 64);
  klp += __shfl_xor(klp, 4, 64);
  klp += __shfl_xor(klp, 8, 64);
  klp += __shfl_xor(klp, 16, 64);
  klp += __shfl_xor(klp, 32, 64);
  const int lane = threadIdx.x & 63, wave = threadIdx.x >> 6;
  if (lane == 0) red[wave] = klp;
  __syncthreads();
  if (threadIdx.x == 0) {
    float s = 0.f;
    for (int w = 0; w < WAVES; ++w) s += red[w];
    atomicAdd(out + B_ * D_, s * (-0.5f / (B_ * K_)));
  }
}

extern "C" void kernel_launch(void* const* d_in, const int* in_sizes, int n_in,
                              void* d_out, int out_size, void* d_ws, size_t ws_size,
                              hipStream_t stream) {
  const float* x    = (const float*)d_in[0];
  const float* W    = (const float*)d_in[1];
  const float* bias = (const float*)d_in[2];
  const float* eps  = (const float*)d_in[3];
  float* out = (float*)d_out;
  float* ws  = (float*)d_ws;

  int ncopy = (ws_size >= (size_t)WS_FLOATS * sizeof(float)) ? NCOPY : 1;
  size_t zero_bytes = (ncopy == NCOPY)
      ? (size_t)WS_FLOATS * sizeof(float)
      : (size_t)(B_ * K_ * D_ * 2 + B_ * K_) * sizeof(float);
  // When ncopy==1 the S0 region still lives at S0_OFF; zero both pieces.
  if (ncopy == NCOPY) {
    hipMemsetAsync(ws, 0, zero_bytes, stream);
  } else {
    hipMemsetAsync(ws, 0, (size_t)(B_ * K_ * D_ * 2) * sizeof(float), stream);
    hipMemsetAsync(ws + S0_OFF, 0, (size_t)(B_ * K_) * sizeof(float), stream);
  }
  hipMemsetAsync(out + B_ * D_, 0, sizeof(float), stream);

  k1_accum<<<B_ * CHUNKS, 64 * WAVES, 0, stream>>>(x, W, bias, ws, ncopy);
  k2_final<<<B_, D_, 0, stream>>>(ws, eps, out, ncopy);
}

// Round 2
// 49.643 us; speedup vs baseline: 9.2017x; 9.2017x over previous
//
#include <hip/hip_runtime.h>

// SoftClusterGaussianHead — one-pass moment formulation.
// B=8, N=4096, D=512, K=8.
// sigma = S2 + (S0-2)*S1^2 with S0=sum_n p, S1=sum_n p*x, S2=sum_n p*x^2.
// Round 2: replace 16.7M global atomics with per-block LDS tree reduction +
// non-atomic per-chunk partial stores (8 MB), fused parallel finalizer.

typedef float v2f __attribute__((ext_vector_type(2)));

#define B_ 8
#define N_ 4096
#define D_ 512
#define K_ 8
#define EPS_ 1e-6f
#define CHUNKS 32          // blocks per b
#define WAVES 8            // per block
#define ROWS_PER_WAVE 16   // 128 rows/block / 8 waves

// ws layout (floats), parameterized by cstride (CHUNKS normally, 1 in
// atomic-fallback mode):
//   partial: [b][chunk][k][d][2]   (S1,S2 interleaved)   B*cstride*K*D*2
//   s0p:     [b][chunk][k]                               B*cstride*K

__global__ __launch_bounds__(512, 2)
void k1_accum(const float* __restrict__ x, const float* __restrict__ W,
              const float* __restrict__ bias, float* __restrict__ ws,
              int cstride, int atomic_mode) {
  const int lane = threadIdx.x & 63;
  const int wave = threadIdx.x >> 6;
  const int b    = blockIdx.x >> 5;
  const int chunk= blockIdx.x & 31;
  const int m    = lane & 7;

  const int d0 = lane * 4;           // owned d: d0..d0+3 and 256+d0..256+d0+3

  // Preload W fragments: wk[dj][kp] = (W[d][2kp], W[d][2kp+1])
  v2f wk[8][4];
#pragma unroll
  for (int c = 0; c < 4; ++c) {
    const float4* wr0 = reinterpret_cast<const float4*>(&W[(d0 + c) * K_]);
    float4 wa = wr0[0], wb = wr0[1];
    wk[c][0] = (v2f){wa.x, wa.y}; wk[c][1] = (v2f){wa.z, wa.w};
    wk[c][2] = (v2f){wb.x, wb.y}; wk[c][3] = (v2f){wb.z, wb.w};
    const float4* wr1 = reinterpret_cast<const float4*>(&W[(256 + d0 + c) * K_]);
    float4 wc = wr1[0], wd = wr1[1];
    wk[4+c][0] = (v2f){wc.x, wc.y}; wk[4+c][1] = (v2f){wc.z, wc.w};
    wk[4+c][2] = (v2f){wd.x, wd.y}; wk[4+c][3] = (v2f){wd.z, wd.w};
  }
  const float biasv = bias[m];

  v2f acc[8][8];
#pragma unroll
  for (int dj = 0; dj < 8; ++dj)
#pragma unroll
    for (int k = 0; k < 8; ++k) acc[dj][k] = (v2f){0.f, 0.f};
  float s0acc = 0.f;

  const bool c0 = (lane & 1) != 0;
  const bool c1 = (lane & 2) != 0;
  const bool c2 = (lane & 4) != 0;

  const int row_base = chunk * (WAVES * ROWS_PER_WAVE) + wave * ROWS_PER_WAVE;
  const float* xb = x + (size_t)b * N_ * D_;

  // software-pipelined row loop
  const float4* xr = reinterpret_cast<const float4*>(&xb[(size_t)row_base * D_]);
  float4 xa = xr[lane];
  float4 xc = xr[64 + lane];

  for (int i = 0; i < ROWS_PER_WAVE; ++i) {
    // prefetch next row (clamped, no OOB)
    const int nrow = row_base + ((i + 1 < ROWS_PER_WAVE) ? i + 1 : i);
    const float4* xrn = reinterpret_cast<const float4*>(&xb[(size_t)nrow * D_]);
    float4 na = xrn[lane];
    float4 nc = xrn[64 + lane];

    float xv[8] = {xa.x, xa.y, xa.z, xa.w, xc.x, xc.y, xc.z, xc.w};

    // partial logits over owned d
    v2f qp[4] = {(v2f){0,0},(v2f){0,0},(v2f){0,0},(v2f){0,0}};
#pragma unroll
    for (int dj = 0; dj < 8; ++dj) {
      v2f xx = (v2f){xv[dj], xv[dj]};
#pragma unroll
      for (int kp = 0; kp < 4; ++kp) qp[kp] += wk[dj][kp] * xx;
    }
    float q0=qp[0].x,q1=qp[0].y,q2=qp[1].x,q3=qp[1].y;
    float q4=qp[2].x,q5=qp[2].y,q6=qp[3].x,q7=qp[3].y;

    // reduce-scatter butterfly: lane ends with full logit for k = lane&7
    float r0 = c0 ? q0 : q1, r1 = c0 ? q2 : q3, r2 = c0 ? q4 : q5, r3 = c0 ? q6 : q7;
    r0 = __shfl_xor(r0, 1, 64); r1 = __shfl_xor(r1, 1, 64);
    r2 = __shfl_xor(r2, 1, 64); r3 = __shfl_xor(r3, 1, 64);
    float a0 = (c0 ? q1 : q0) + r0, a1 = (c0 ? q3 : q2) + r1;
    float a2 = (c0 ? q5 : q4) + r2, a3 = (c0 ? q7 : q6) + r3;
    float s0g = c1 ? a0 : a1, s1g = c1 ? a2 : a3;
    s0g = __shfl_xor(s0g, 2, 64); s1g = __shfl_xor(s1g, 2, 64);
    float b0 = (c1 ? a1 : a0) + s0g, b1 = (c1 ? a3 : a2) + s1g;
    float g0 = c2 ? b0 : b1;
    g0 = __shfl_xor(g0, 4, 64);
    float t = (c2 ? b1 : b0) + g0;
    t += __shfl_xor(t, 8, 64);
    t += __shfl_xor(t, 16, 64);
    t += __shfl_xor(t, 32, 64);
    t += biasv;

    // softmax in transposed (one-k-per-lane) form
    float mx = fmaxf(t, __shfl_xor(t, 1, 64));
    mx = fmaxf(mx, __shfl_xor(mx, 2, 64));
    mx = fmaxf(mx, __shfl_xor(mx, 4, 64));
    float e = __expf(t - mx);
    float se = e + __shfl_xor(e, 1, 64);
    se += __shfl_xor(se, 2, 64);
    se += __shfl_xor(se, 4, 64);
    float pm = e * __builtin_amdgcn_rcpf(se);
    s0acc += pm;

    // gather p[0..7] to every lane: src = (lane & 0x18) | k within 32-half
    float p[8];
#define GATH(KK) p[KK] = __int_as_float(__builtin_amdgcn_ds_swizzle(__float_as_int(pm), ((KK) << 5) | 0x18))
    GATH(0); GATH(1); GATH(2); GATH(3); GATH(4); GATH(5); GATH(6); GATH(7);
#undef GATH

    // accumulate packed (S1,S2)
#pragma unroll
    for (int dj = 0; dj < 8; ++dj) {
      v2f m2 = (v2f){xv[dj], xv[dj] * xv[dj]};
#pragma unroll
      for (int k = 0; k < 8; ++k) {
        v2f pp = (v2f){p[k], p[k]};
        acc[dj][k] += m2 * pp;
      }
    }

    xa = na; xc = nc;
  }

  // ---- block-level reduction & flush (no global atomics in normal mode) ----
  float* partial = ws;
  float* s0p = ws + (size_t)B_ * cstride * K_ * D_ * 2;
  const int cslot = atomic_mode ? 0 : chunk;

  __shared__ float s0sh[WAVES][K_];
  __shared__ v2f sh[WAVES][2][K_][64];   // 64 KB

  if (lane < K_) s0sh[wave][lane] = s0acc;   // s0acc already wave-complete (replicated)
  __syncthreads();
  if (threadIdx.x < K_) {
    float s = 0.f;
#pragma unroll
    for (int w = 0; w < WAVES; ++w) s += s0sh[w][threadIdx.x];
    float* dst = s0p + (size_t)(b * cstride + cslot) * K_ + threadIdx.x;
    if (atomic_mode) atomicAdd(dst, s); else *dst = s;
  }

#pragma unroll
  for (int r = 0; r < 4; ++r) {
#pragma unroll
    for (int k = 0; k < 8; ++k) {
      sh[wave][0][k][lane] = acc[2*r][k];
      sh[wave][1][k][lane] = acc[2*r + 1][k];
    }
    __syncthreads();
    // wave w reduces k=w across waves; lanes cover the 64 d-slots
    v2f sA = sh[0][0][wave][lane];
    v2f sB = sh[0][1][wave][lane];
#pragma unroll
    for (int w = 1; w < WAVES; ++w) {
      sA += sh[w][0][wave][lane];
      sB += sh[w][1][wave][lane];
    }
    const int d = (r < 2) ? (lane * 4 + 2 * r) : (256 + lane * 4 + (2 * r - 4));
    float* dst = partial + (((size_t)(b * cstride + cslot) * K_ + wave) * D_ + d) * 2;
    if (atomic_mode) {
      atomicAdd(dst + 0, sA.x); atomicAdd(dst + 1, sA.y);
      atomicAdd(dst + 2, sB.x); atomicAdd(dst + 3, sB.y);
    } else {
      float4 v; v.x = sA.x; v.y = sA.y; v.z = sB.x; v.w = sB.y;
      *reinterpret_cast<float4*>(dst) = v;   // d even -> 16B aligned
    }
    __syncthreads();
  }
}

// Fused finalizer: grid = B*32 blocks, 128 threads (8 k x 16 d).
__global__ __launch_bounds__(128)
void k2_final(const float* __restrict__ ws, const float* __restrict__ eps,
              float* __restrict__ out, int cstride, int nchunks) {
  const int b = blockIdx.x >> 5;
  const int slice = blockIdx.x & 31;
  const int tid = threadIdx.x;
  const int k = tid >> 4;
  const int dl = tid & 15;
  const int d = slice * 16 + dl;

  const float* partial = ws;
  const float* s0p = ws + (size_t)B_ * cstride * K_ * D_ * 2;

  __shared__ float s0sh[K_];
  __shared__ float zsh[K_][16];
  __shared__ float klsh[2];

  if (tid < K_) {
    float s = 0.f;
    for (int c = 0; c < nchunks; ++c) s += s0p[(size_t)(b * cstride + c) * K_ + tid];
    s0sh[tid] = s;
  }
  __syncthreads();

  float S1 = 0.f, S2 = 0.f;
  for (int c = 0; c < nchunks; ++c) {
    const v2f v = *reinterpret_cast<const v2f*>(
        partial + (((size_t)(b * cstride + c) * K_ + k) * D_ + d) * 2);
    S1 += v.x; S2 += v.y;
  }
  const float S0 = s0sh[k];
  float sigraw = S2 + (S0 - 2.f) * S1 * S1;
  float sig = fmaxf(sigraw, 0.f) + EPS_;
  float z = S1 + eps[((size_t)(b * K_ + k)) * D_ + d] * sqrtf(sig);
  zsh[k][dl] = z;
  float klp = 1.f + logf(sig) - S1 * S1 - sigraw;

  klp += __shfl_xor(klp, 1, 64);
  klp += __shfl_xor(klp, 2, 64);
  klp += __shfl_xor(klp, 4, 64);
  klp += __shfl_xor(klp, 8, 64);
  klp += __shfl_xor(klp, 16, 64);
  klp += __shfl_xor(klp, 32, 64);
  const int lane = tid & 63, wv = tid >> 6;
  if (lane == 0) klsh[wv] = klp;
  __syncthreads();

  if (tid < 16) {
    float pooled = 0.f;
#pragma unroll
    for (int kk = 0; kk < K_; ++kk) pooled += zsh[kk][tid];
    out[b * D_ + slice * 16 + tid] = pooled * 0.125f;
  }
  if (tid == 0) {
    atomicAdd(out + B_ * D_, (klsh[0] + klsh[1]) * (-0.5f / (B_ * K_)));
  }
}

extern "C" void kernel_launch(void* const* d_in, const int* in_sizes, int n_in,
                              void* d_out, int out_size, void* d_ws, size_t ws_size,
                              hipStream_t stream) {
  const float* x    = (const float*)d_in[0];
  const float* W    = (const float*)d_in[1];
  const float* bias = (const float*)d_in[2];
  const float* eps  = (const float*)d_in[3];
  float* out = (float*)d_out;
  float* ws  = (float*)d_ws;

  const size_t full_floats = (size_t)B_ * CHUNKS * K_ * D_ * 2 + (size_t)B_ * CHUNKS * K_;
  const int atomic_mode = (ws_size < full_floats * sizeof(float)) ? 1 : 0;
  const int cstride = atomic_mode ? 1 : CHUNKS;
  const int nchunks = atomic_mode ? 1 : CHUNKS;

  if (atomic_mode) {
    // zero the single-copy accumulators (contiguous: partial then s0p)
    const size_t zbytes = ((size_t)B_ * 1 * K_ * D_ * 2 + (size_t)B_ * 1 * K_) * sizeof(float);
    hipMemsetAsync(ws, 0, zbytes, stream);
  }
  hipMemsetAsync(out + B_ * D_, 0, sizeof(float), stream);

  k1_accum<<<B_ * CHUNKS, 64 * WAVES, 0, stream>>>(x, W, bias, ws, cstride, atomic_mode);
  k2_final<<<B_ * CHUNKS, 128, 0, stream>>>(ws, eps, out, cstride, nchunks);
}